// Round 7
// baseline (1017.138 us; speedup 1.0000x reference)
//
#include <hip/hip_runtime.h>
#include <stdint.h>

typedef __attribute__((ext_vector_type(8))) short short8;
typedef __attribute__((ext_vector_type(4))) short short4_t;
typedef __attribute__((ext_vector_type(4))) float f32x4;
typedef unsigned short u16;
typedef unsigned int u32;

#define C_ 512

__device__ __forceinline__ u16 f2b(float f){
  u32 u = __float_as_uint(f);
  u += 0x7FFFu + ((u >> 16) & 1u);
  return (u16)(u >> 16);
}
__device__ __forceinline__ float b2f(u16 h){ return __uint_as_float(((u32)h) << 16); }

__device__ __forceinline__ short8 cvt8(float4 lo, float4 hi){
  short8 r;
  r[0]=(short)f2b(lo.x); r[1]=(short)f2b(lo.y); r[2]=(short)f2b(lo.z); r[3]=(short)f2b(lo.w);
  r[4]=(short)f2b(hi.x); r[5]=(short)f2b(hi.y); r[6]=(short)f2b(hi.z); r[7]=(short)f2b(hi.w);
  return r;
}

// ---------------- prep: k2/v2 = agent @ W + b ----------------
__global__ __launch_bounds__(256) void prep_kv(
    const float* __restrict__ agent_k, const float* __restrict__ Wk, const float* __restrict__ bk,
    const float* __restrict__ agent_v, const float* __restrict__ Wv, const float* __restrict__ bv,
    float* __restrict__ k2, float* __restrict__ v2)
{
  const int kv = blockIdx.x >> 4;
  const int c0 = (blockIdx.x & 15) * 32;
  const int t = threadIdx.x;
  const float* ag = kv ? agent_v : agent_k;
  const float* W  = kv ? Wv : Wk;
  const float* bb = kv ? bv : bk;
  float* dst      = kv ? v2 : k2;

  __shared__ float ash[16*512];
  __shared__ float part[8][16][32];
  for (int i = t; i < 8192; i += 256) ash[i] = ag[i];
  __syncthreads();

  const int cl = t & 31, ks = t >> 5;
  float s[16];
  #pragma unroll
  for (int a = 0; a < 16; ++a) s[a] = 0.f;
  for (int i = 0; i < 64; ++i) {
    const int cc = ks*64 + i;
    const float wv = W[(size_t)cc*C_ + c0 + cl];
    #pragma unroll
    for (int a = 0; a < 16; ++a) s[a] += ash[a*512 + cc] * wv;
  }
  #pragma unroll
  for (int a = 0; a < 16; ++a) part[ks][a][cl] = s[a];
  __syncthreads();
  for (int p = t; p < 512; p += 256) {
    const int a = p >> 5, c = p & 31;
    float v = bb[c0 + c];
    #pragma unroll
    for (int k = 0; k < 8; ++k) v += part[k][a][c];
    dst[a*C_ + c0 + c] = v;
  }
}

__global__ void prep_wqk(const float* __restrict__ Wq, const float* __restrict__ bq,
                         const float* __restrict__ k2, u16* __restrict__ WqkT, float* __restrict__ bqk)
{
  int c = blockIdx.x, t = threadIdx.x; // t = ha in [0,128)
  int h = t >> 4, a = t & 15;
  float s = 0.f;
  for (int d = 0; d < 64; ++d) s += Wq[c*C_ + h*64 + d] * k2[a*C_ + h*64 + d];
  WqkT[t*C_ + c] = f2b(s * 0.125f);
  if (c == 0){
    float sb = 0.f;
    for (int d = 0; d < 64; ++d) sb += bq[h*64 + d] * k2[a*C_ + h*64 + d];
    bqk[t] = sb * 0.125f;
  }
}

__global__ void prep_wvp(const float* __restrict__ Wp, const float* __restrict__ v2, u16* __restrict__ WvpT)
{
  int ha = blockIdx.x; int h = ha >> 4, a = ha & 15;
  __shared__ float vsh[64];
  if (threadIdx.x < 64) vsh[threadIdx.x] = v2[a*C_ + h*64 + threadIdx.x];
  __syncthreads();
  for (int co = threadIdx.x; co < C_; co += 256){
    float s = 0.f;
    for (int d = 0; d < 64; ++d) s += vsh[d] * Wp[(h*64 + d)*C_ + co];
    WvpT[co*128 + ha] = f2b(s);
  }
}

// ---------------- pass A: 32KB B-LDS x 4 K-phases, depth-2 register ring ----------------
// bmask lets a probe grid repeat the same work: m0 = (bx & bmask)*128.
__global__ __launch_bounds__(256, 4) void pass_a(
    const float* __restrict__ x, const u16* __restrict__ WqkT,
    const float* __restrict__ bqk, u16* __restrict__ attn,
    float* __restrict__ gpart, int bmask)
{
  __shared__ u16 Bs[128*128];          // 32 KB: row=ha, 128 k-elems (256 B), XOR-swizzled
  __shared__ float ps[4][16], pm[4][16];

  const int t = threadIdx.x;
  const int bxm = blockIdx.x & bmask;
  const int m0 = bxm * 128;
  const int w = t >> 6, lane = t & 63;
  const int la = lane & 15, rg = lane >> 4;

  const float* xr0 = x + (size_t)(m0 + w*32 + la)*C_ + rg*8;
  const float* xr1 = xr0 + 16*C_;

  const int srow = t >> 1, shalf = t & 1;
  const u16* ssrc = WqkT + (size_t)srow*C_ + shalf*64;
  char* sdst = (char*)Bs + srow*256;
  const int sxor = (srow & 7) << 4;

  f32x4 acc[2][8];
  #pragma unroll
  for (int i = 0; i < 2; ++i)
    #pragma unroll
    for (int j = 0; j < 8; ++j) acc[i][j] = (f32x4){0.f,0.f,0.f,0.f};

  float4 pr0[2][2], pr1[2][2];         // depth-2 kt ring (32 VGPR)
#define LOADKT(slot, kt) \
  pr0[slot][0] = *(const float4*)(xr0 + (kt)*32);     \
  pr0[slot][1] = *(const float4*)(xr0 + (kt)*32 + 4); \
  pr1[slot][0] = *(const float4*)(xr1 + (kt)*32);     \
  pr1[slot][1] = *(const float4*)(xr1 + (kt)*32 + 4);

  LOADKT(0, 0); LOADKT(1, 1);

  #pragma unroll
  for (int ph = 0; ph < 4; ++ph) {
    __syncthreads();
    #pragma unroll
    for (int i = 0; i < 8; ++i) {
      short8 v = *(const short8*)(ssrc + ph*128 + i*8);
      *(short8*)(sdst + ((shalf*128 + i*16) ^ sxor)) = v;
    }
    __syncthreads();
    #pragma unroll
    for (int k4 = 0; k4 < 4; ++k4) {
      const int kt = ph*4 + k4;
      const int sl = kt & 1;
      short8 b0 = cvt8(pr0[sl][0], pr0[sl][1]);
      short8 b1 = cvt8(pr1[sl][0], pr1[sl][1]);
      if (kt < 14) { LOADKT(sl, kt + 2); }
      #pragma unroll
      for (int ct = 0; ct < 8; ++ct) {
        const int row = ct*16 + la;
        short8 af = *(const short8*)((const char*)Bs + row*256 + ((k4*64 + rg*16) ^ ((row & 7) << 4)));
        acc[0][ct] = __builtin_amdgcn_mfma_f32_16x16x32_bf16(af, b0, acc[0][ct], 0, 0, 0);
        acc[1][ct] = __builtin_amdgcn_mfma_f32_16x16x32_bf16(af, b1, acc[1][ct], 0, 0, 0);
      }
    }
  }
#undef LOADKT

  // epilogue: softmax over a (in-register) + attn write + gating partials
  float psj[4] = {0.f,0.f,0.f,0.f};
  float pmj[4] = {0.f,0.f,0.f,0.f};

  #pragma unroll
  for (int nt = 0; nt < 2; ++nt) {
    const int row = m0 + w*32 + nt*16 + la;
    #pragma unroll
    for (int ct = 0; ct < 8; ++ct) {
      float4 bb = *(const float4*)(bqk + ct*16 + rg*4);
      float e0 = __expf(acc[nt][ct][0] + bb.x);
      float e1 = __expf(acc[nt][ct][1] + bb.y);
      float e2 = __expf(acc[nt][ct][2] + bb.z);
      float e3 = __expf(acc[nt][ct][3] + bb.w);
      float s = e0 + e1 + e2 + e3;
      s += __shfl_xor(s, 16); s += __shfl_xor(s, 32);
      float r = __builtin_amdgcn_rcpf(s);
      float p0 = e0*r, p1 = e1*r, p2 = e2*r, p3 = e3*r;
      psj[0] += p0; psj[1] += p1; psj[2] += p2; psj[3] += p3;
      pmj[0] = fmaxf(pmj[0], p0); pmj[1] = fmaxf(pmj[1], p1);
      pmj[2] = fmaxf(pmj[2], p2); pmj[3] = fmaxf(pmj[3], p3);
      short4_t st;
      st[0]=(short)f2b(p0); st[1]=(short)f2b(p1); st[2]=(short)f2b(p2); st[3]=(short)f2b(p3);
      *(short4_t*)(attn + (size_t)row*128 + ct*16 + rg*4) = st;
    }
  }

  #pragma unroll
  for (int j = 0; j < 4; ++j) {
    float s = psj[j], m = pmj[j];
    s += __shfl_xor(s, 1); s += __shfl_xor(s, 2); s += __shfl_xor(s, 4); s += __shfl_xor(s, 8);
    m = fmaxf(m, __shfl_xor(m, 1)); m = fmaxf(m, __shfl_xor(m, 2));
    m = fmaxf(m, __shfl_xor(m, 4)); m = fmaxf(m, __shfl_xor(m, 8));
    if (la == 0) { ps[w][rg*4+j] = s; pm[w][rg*4+j] = m; }
  }
  __syncthreads();
  if (t < 16) {
    float s = ps[0][t] + ps[1][t] + ps[2][t] + ps[3][t];
    float m = fmaxf(fmaxf(pm[0][t], pm[1][t]), fmaxf(pm[2][t], pm[3][t]));
    gpart[(size_t)bxm*32 + t]      = s;
    gpart[(size_t)bxm*32 + 16 + t] = m;
  }
}

// ---------------- pass B: gate fused, W-tile in 32KB LDS, attn prefetched, XCD-swizzled -------
__global__ __launch_bounds__(256, 4) void pass_b(
    const u16* __restrict__ attn, const u16* __restrict__ WvpT,
    const float* __restrict__ gpart, const float* __restrict__ ca_w1,
    const float* __restrict__ ca_w2, const float* __restrict__ bp,
    float* __restrict__ out, int bmask)
{
  __shared__ u16 Bs[128*128];          // 32 KB
  __shared__ float gsh[16];
  const int bxm = blockIdx.x & bmask;
  const int lg = (bxm & 7)*512 + (bxm >> 3);
  const int mb = lg >> 2, cb = lg & 3;
  const int b = mb >> 5;
  const int t = threadIdx.x;
  const int w = t >> 6, lane = t & 63;
  const int la = lane & 15, rg = lane >> 4;

  // prefetch all attn fragments (K=128 -> 4 kt) — independent of everything below
  const u16* br0 = attn + (size_t)(mb*128 + w*32 + la)*128 + rg*8;
  const u16* br1 = br0 + 16*128;
  short8 bf0[4], bf1[4];
  #pragma unroll
  for (int kt = 0; kt < 4; ++kt) {
    bf0[kt] = *(const short8*)(br0 + kt*32);
    bf1[kt] = *(const short8*)(br1 + kt*32);
  }

  // gate MLP from per-block partials (t<16)
  if (t < 16) {
    float s = 0.f, m = 0.f;
    #pragma unroll 4
    for (int blk = 0; blk < 32; ++blk) {
      const float* gp = gpart + (size_t)(b*32 + blk)*32;
      s += gp[t]; m = fmaxf(m, gp[16 + t]);
    }
    float c1 = s * (1.0f/32768.0f) * ca_w1[t];
    float c2 = m * ca_w1[t];
    c1 += __shfl_xor(c1, 1); c1 += __shfl_xor(c1, 2); c1 += __shfl_xor(c1, 4); c1 += __shfl_xor(c1, 8);
    c2 += __shfl_xor(c2, 1); c2 += __shfl_xor(c2, 2); c2 += __shfl_xor(c2, 4); c2 += __shfl_xor(c2, 8);
    float g1 = fmaxf(c1, 0.f) + fmaxf(c2, 0.f);
    gsh[t] = 1.f / (1.f + __expf(-g1 * ca_w2[t]));
  }
  __syncthreads();

  // stage WvpT tile with gate applied (gate idx = ha & 15 = (i&1)*8 + j)
  const int srow = t >> 1, shalf = t & 1;
  const u16* ssrc = WvpT + (size_t)(cb*128 + srow)*128 + shalf*64;
  char* sdst = (char*)Bs + srow*256;
  const int sxor = (srow & 7) << 4;
  #pragma unroll
  for (int i = 0; i < 8; ++i) {
    short8 q = *(const short8*)(ssrc + i*8);
    const float* g = &gsh[(i & 1) * 8];
    short8 r;
    #pragma unroll
    for (int j = 0; j < 8; ++j) r[j] = (short)f2b(b2f((u16)q[j]) * g[j]);
    *(short8*)(sdst + ((shalf*128 + i*16) ^ sxor)) = r;
  }
  __syncthreads();

  f32x4 acc[2][8];
  #pragma unroll
  for (int i = 0; i < 2; ++i)
    #pragma unroll
    for (int j = 0; j < 8; ++j) acc[i][j] = (f32x4){0.f,0.f,0.f,0.f};

  #pragma unroll
  for (int kt = 0; kt < 4; ++kt) {
    #pragma unroll
    for (int ct = 0; ct < 8; ++ct) {
      const int row = ct*16 + la;
      short8 af = *(const short8*)((const char*)Bs + row*256 + ((kt*64 + rg*16) ^ ((row & 7) << 4)));
      acc[0][ct] = __builtin_amdgcn_mfma_f32_16x16x32_bf16(af, bf0[kt], acc[0][ct], 0, 0, 0);
      acc[1][ct] = __builtin_amdgcn_mfma_f32_16x16x32_bf16(af, bf1[kt], acc[1][ct], 0, 0, 0);
    }
  }

  // C[co = cb*128 + ct*16 + rg*4 + j][m = mb*128 + w*32 + nt*16 + la] -> float4 stores
  #pragma unroll
  for (int nt = 0; nt < 2; ++nt) {
    const size_t row = (size_t)(mb*128 + w*32 + nt*16 + la);
    #pragma unroll
    for (int ct = 0; ct < 8; ++ct) {
      const int col = cb*128 + ct*16 + rg*4;
      float4 bb = *(const float4*)(bp + col);
      float4 o;
      o.x = acc[nt][ct][0] + bb.x;
      o.y = acc[nt][ct][1] + bb.y;
      o.z = acc[nt][ct][2] + bb.z;
      o.w = acc[nt][ct][3] + bb.w;
      *(float4*)(out + row*C_ + col) = o;
    }
  }
}

// ---------------- launch ----------------
extern "C" void kernel_launch(void* const* d_in, const int* in_sizes, int n_in,
                              void* d_out, int out_size, void* d_ws, size_t ws_size,
                              hipStream_t stream)
{
  const float* x       = (const float*)d_in[0];
  const float* Wq      = (const float*)d_in[1];
  const float* bq      = (const float*)d_in[2];
  const float* Wk      = (const float*)d_in[3];
  const float* bk      = (const float*)d_in[4];
  const float* Wv      = (const float*)d_in[5];
  const float* bv      = (const float*)d_in[6];
  const float* Wp      = (const float*)d_in[7];
  const float* bp      = (const float*)d_in[8];
  const float* agent_k = (const float*)d_in[9];
  const float* agent_v = (const float*)d_in[10];
  const float* ca_w1   = (const float*)d_in[11];
  const float* ca_w2   = (const float*)d_in[12];
  float* out = (float*)d_out;

  char* ws = (char*)d_ws;
  u16*   attn  = (u16*)(ws);                          // 33,554,432 B
  float* k2    = (float*)(ws + 33554432);             // 32768
  float* v2    = (float*)(ws + 33587200);             // 32768
  u16*   WqkT  = (u16*)(ws + 33619968);               // 131072
  float* bqk   = (float*)(ws + 33751040);             // 2048
  u16*   WvpT  = (u16*)(ws + 33753088);               // 131072
  float* gpart = (float*)(ws + 33884160);             // 131072

  // probe scratch (diagnostic only)
  u16*   attn2  = (u16*)(ws + 50331648);              // 33,554,432
  float* gpart2 = (float*)(ws + 83886080);            // 131072
  float* out2   = (float*)(ws + 100663296);           // 268,435,456  -> ends 369,098,752

  prep_kv<<<32, 256, 0, stream>>>(agent_k, Wk, bk, agent_v, Wv, bv, k2, v2);
  prep_wqk<<<512, 128, 0, stream>>>(Wq, bq, k2, WqkT, bqk);
  prep_wvp<<<128, 256, 0, stream>>>(Wp, v2, WvpT);
  pass_a<<<1024, 256, 0, stream>>>(x, WqkT, bqk, attn, gpart, 1023);
  pass_b<<<4096, 256, 0, stream>>>(attn, WvpT, gpart, ca_w1, ca_w2, bp, out, 4095);

  // ---- diagnostic probes: identical code, 4x grid, scratch outputs ----
  if (ws_size >= 369098752ull) {
    pass_a<<<4096, 256, 0, stream>>>(x, WqkT, bqk, attn2, gpart2, 1023);
    pass_b<<<16384, 256, 0, stream>>>(attn, WvpT, gpart, ca_w1, ca_w2, bp, out2, 4095);
  }
}

// Round 8
// 228.688 us; speedup vs baseline: 4.4477x; 4.4477x over previous
//
#include <hip/hip_runtime.h>
#include <stdint.h>

typedef __attribute__((ext_vector_type(8))) short short8;
typedef __attribute__((ext_vector_type(4))) short short4_t;
typedef __attribute__((ext_vector_type(4))) float f32x4;
typedef unsigned short u16;
typedef unsigned int u32;

#define C_ 512

__device__ __forceinline__ u16 f2b(float f){
  u32 u = __float_as_uint(f);
  u += 0x7FFFu + ((u >> 16) & 1u);
  return (u16)(u >> 16);
}
__device__ __forceinline__ float b2f(u16 h){ return __uint_as_float(((u32)h) << 16); }

__device__ __forceinline__ short8 cvt8(float4 lo, float4 hi){
  short8 r;
  r[0]=(short)f2b(lo.x); r[1]=(short)f2b(lo.y); r[2]=(short)f2b(lo.z); r[3]=(short)f2b(lo.w);
  r[4]=(short)f2b(hi.x); r[5]=(short)f2b(hi.y); r[6]=(short)f2b(hi.z); r[7]=(short)f2b(hi.w);
  return r;
}

// ---------------- prep: k2/v2 = agent @ W + b ----------------
__global__ __launch_bounds__(256) void prep_kv(
    const float* __restrict__ agent_k, const float* __restrict__ Wk, const float* __restrict__ bk,
    const float* __restrict__ agent_v, const float* __restrict__ Wv, const float* __restrict__ bv,
    float* __restrict__ k2, float* __restrict__ v2)
{
  const int kv = blockIdx.x >> 4;
  const int c0 = (blockIdx.x & 15) * 32;
  const int t = threadIdx.x;
  const float* ag = kv ? agent_v : agent_k;
  const float* W  = kv ? Wv : Wk;
  const float* bb = kv ? bv : bk;
  float* dst      = kv ? v2 : k2;

  __shared__ float ash[16*512];
  __shared__ float part[8][16][32];
  for (int i = t; i < 8192; i += 256) ash[i] = ag[i];
  __syncthreads();

  const int cl = t & 31, ks = t >> 5;
  float s[16];
  #pragma unroll
  for (int a = 0; a < 16; ++a) s[a] = 0.f;
  for (int i = 0; i < 64; ++i) {
    const int cc = ks*64 + i;
    const float wv = W[(size_t)cc*C_ + c0 + cl];
    #pragma unroll
    for (int a = 0; a < 16; ++a) s[a] += ash[a*512 + cc] * wv;
  }
  #pragma unroll
  for (int a = 0; a < 16; ++a) part[ks][a][cl] = s[a];
  __syncthreads();
  for (int p = t; p < 512; p += 256) {
    const int a = p >> 5, c = p & 31;
    float v = bb[c0 + c];
    #pragma unroll
    for (int k = 0; k < 8; ++k) v += part[k][a][c];
    dst[a*C_ + c0 + c] = v;
  }
}

// WqkTr fragment-linear: idx = ((kt*8 + ct)*64 + rg*16 + la)*8 + e
// where value = scale * sum_d Wq[c][h*64+d] * k2[a][h*64+d], ha = ct*16+la (h=ha>>4,a=ha&15),
// c = kt*32 + rg*8 + e.
__global__ void prep_wqk(const float* __restrict__ Wq, const float* __restrict__ bq,
                         const float* __restrict__ k2, u16* __restrict__ WqkTr, float* __restrict__ bqk)
{
  int c = blockIdx.x, t = threadIdx.x; // t = ha in [0,128)
  int h = t >> 4, a = t & 15;
  float s = 0.f;
  for (int d = 0; d < 64; ++d) s += Wq[c*C_ + h*64 + d] * k2[a*C_ + h*64 + d];
  const int kt = c >> 5, rg = (c >> 3) & 3, e = c & 7;
  const int ct = t >> 4, la = t & 15;
  WqkTr[(((kt*8 + ct)*64) + rg*16 + la)*8 + e] = f2b(s * 0.125f);
  if (c == 0){
    float sb = 0.f;
    for (int d = 0; d < 64; ++d) sb += bq[h*64 + d] * k2[a*C_ + h*64 + d];
    bqk[t] = sb * 0.125f;
  }
}

// WvpTr fragment-linear: idx = (((cb*4 + kt)*8 + ct)*64 + rg*16 + la)*8 + e
// value = sum_d v2[a][h*64+d] * Wp[(h*64+d)][co]; co = cb*128 + ct*16 + la; ha = kt*32 + rg*8 + e.
__global__ void prep_wvp(const float* __restrict__ Wp, const float* __restrict__ v2, u16* __restrict__ WvpTr)
{
  int ha = blockIdx.x; int h = ha >> 4, a = ha & 15;
  __shared__ float vsh[64];
  if (threadIdx.x < 64) vsh[threadIdx.x] = v2[a*C_ + h*64 + threadIdx.x];
  __syncthreads();
  const int kt = ha >> 5, rg = (ha >> 3) & 3, e = ha & 7;
  for (int co = threadIdx.x; co < C_; co += 256){
    float s = 0.f;
    for (int d = 0; d < 64; ++d) s += vsh[d] * Wp[(h*64 + d)*C_ + co];
    const int cb = co >> 7, ct = (co >> 4) & 7, la = co & 15;
    WvpTr[((((cb*4 + kt)*8 + ct)*64) + rg*16 + la)*8 + e] = f2b(s);
  }
}

// ---------------- pass A: fragment-linear B in LDS (zero-conflict), depth-2 x ring ----------------
__global__ __launch_bounds__(256, 4) void pass_a(
    const float* __restrict__ x, const u16* __restrict__ WqkTr,
    const float* __restrict__ bqk, u16* __restrict__ attn,
    float* __restrict__ gpart)
{
  __shared__ __align__(16) u16 Bs[16384];   // 32 KB, fragment-linear per phase
  __shared__ float ps[4][16], pm[4][16];

  const int t = threadIdx.x;
  const int m0 = blockIdx.x * 128;
  const int w = t >> 6, lane = t & 63;
  const int la = lane & 15, rg = lane >> 4;

  const float* xr0 = x + (size_t)(m0 + w*32 + la)*C_ + rg*8;
  const float* xr1 = xr0 + 16*C_;

  f32x4 acc[2][8];
  #pragma unroll
  for (int i = 0; i < 2; ++i)
    #pragma unroll
    for (int j = 0; j < 8; ++j) acc[i][j] = (f32x4){0.f,0.f,0.f,0.f};

  float4 pr0[2][2], pr1[2][2];         // depth-2 kt ring (32 VGPR)
#define LOADKT(slot, kt) \
  pr0[slot][0] = *(const float4*)(xr0 + (kt)*32);     \
  pr0[slot][1] = *(const float4*)(xr0 + (kt)*32 + 4); \
  pr1[slot][0] = *(const float4*)(xr1 + (kt)*32);     \
  pr1[slot][1] = *(const float4*)(xr1 + (kt)*32 + 4);

  LOADKT(0, 0); LOADKT(1, 1);

  #pragma unroll
  for (int ph = 0; ph < 4; ++ph) {
    __syncthreads();
    {
      // linear 32 KB copy: lane-consecutive 16B -> zero bank conflicts
      const short8* gs = (const short8*)WqkTr + ph*2048 + t;
      short8* ld = (short8*)Bs + t;
      #pragma unroll
      for (int i = 0; i < 8; ++i) ld[i*256] = gs[i*256];
    }
    __syncthreads();
    #pragma unroll
    for (int k4 = 0; k4 < 4; ++k4) {
      const int kt = ph*4 + k4;
      const int sl = kt & 1;
      short8 b0 = cvt8(pr0[sl][0], pr0[sl][1]);
      short8 b1 = cvt8(pr1[sl][0], pr1[sl][1]);
      if (kt < 14) { LOADKT(sl, kt + 2); }
      const u16* fb = Bs + (size_t)k4*4096 + lane*8;
      #pragma unroll
      for (int ct = 0; ct < 8; ++ct) {
        short8 af = *(const short8*)(fb + ct*512);
        acc[0][ct] = __builtin_amdgcn_mfma_f32_16x16x32_bf16(af, b0, acc[0][ct], 0, 0, 0);
        acc[1][ct] = __builtin_amdgcn_mfma_f32_16x16x32_bf16(af, b1, acc[1][ct], 0, 0, 0);
      }
    }
  }
#undef LOADKT

  // epilogue: softmax over a (in-register) + attn write + gating partials
  float psj[4] = {0.f,0.f,0.f,0.f};
  float pmj[4] = {0.f,0.f,0.f,0.f};

  #pragma unroll
  for (int nt = 0; nt < 2; ++nt) {
    const int row = m0 + w*32 + nt*16 + la;
    #pragma unroll
    for (int ct = 0; ct < 8; ++ct) {
      float4 bb = *(const float4*)(bqk + ct*16 + rg*4);
      float e0 = __expf(acc[nt][ct][0] + bb.x);
      float e1 = __expf(acc[nt][ct][1] + bb.y);
      float e2 = __expf(acc[nt][ct][2] + bb.z);
      float e3 = __expf(acc[nt][ct][3] + bb.w);
      float s = e0 + e1 + e2 + e3;
      s += __shfl_xor(s, 16); s += __shfl_xor(s, 32);
      float r = __builtin_amdgcn_rcpf(s);
      float p0 = e0*r, p1 = e1*r, p2 = e2*r, p3 = e3*r;
      psj[0] += p0; psj[1] += p1; psj[2] += p2; psj[3] += p3;
      pmj[0] = fmaxf(pmj[0], p0); pmj[1] = fmaxf(pmj[1], p1);
      pmj[2] = fmaxf(pmj[2], p2); pmj[3] = fmaxf(pmj[3], p3);
      short4_t st;
      st[0]=(short)f2b(p0); st[1]=(short)f2b(p1); st[2]=(short)f2b(p2); st[3]=(short)f2b(p3);
      *(short4_t*)(attn + (size_t)row*128 + ct*16 + rg*4) = st;
    }
  }

  #pragma unroll
  for (int j = 0; j < 4; ++j) {
    float s = psj[j], m = pmj[j];
    s += __shfl_xor(s, 1); s += __shfl_xor(s, 2); s += __shfl_xor(s, 4); s += __shfl_xor(s, 8);
    m = fmaxf(m, __shfl_xor(m, 1)); m = fmaxf(m, __shfl_xor(m, 2));
    m = fmaxf(m, __shfl_xor(m, 4)); m = fmaxf(m, __shfl_xor(m, 8));
    if (la == 0) { ps[w][rg*4+j] = s; pm[w][rg*4+j] = m; }
  }
  __syncthreads();
  if (t < 16) {
    float s = ps[0][t] + ps[1][t] + ps[2][t] + ps[3][t];
    float m = fmaxf(fmaxf(pm[0][t], pm[1][t]), fmaxf(pm[2][t], pm[3][t]));
    gpart[(size_t)blockIdx.x*32 + t]      = s;
    gpart[(size_t)blockIdx.x*32 + 16 + t] = m;
  }
}

// ---------------- pass B: gate on P-frags, fragment-linear W in LDS, XCD-swizzled ----------------
__global__ __launch_bounds__(256, 4) void pass_b(
    const u16* __restrict__ attn, const u16* __restrict__ WvpTr,
    const float* __restrict__ gpart, const float* __restrict__ ca_w1,
    const float* __restrict__ ca_w2, const float* __restrict__ bp,
    float* __restrict__ out)
{
  __shared__ __align__(16) u16 Bs[16384];   // 32 KB
  __shared__ float gsh[16];
  const int bx = blockIdx.x;
  const int lg = (bx & 7)*512 + (bx >> 3);
  const int mb = lg >> 2, cb = lg & 3;
  const int b = mb >> 5;
  const int t = threadIdx.x;
  const int w = t >> 6, lane = t & 63;
  const int la = lane & 15, rg = lane >> 4;

  // prefetch all attn fragments (K=128 -> 4 kt)
  const u16* br0 = attn + (size_t)(mb*128 + w*32 + la)*128 + rg*8;
  const u16* br1 = br0 + 16*128;
  short8 bf0[4], bf1[4];
  #pragma unroll
  for (int kt = 0; kt < 4; ++kt) {
    bf0[kt] = *(const short8*)(br0 + kt*32);
    bf1[kt] = *(const short8*)(br1 + kt*32);
  }

  // gate MLP from per-block partials (t<16)
  if (t < 16) {
    float s = 0.f, m = 0.f;
    #pragma unroll 4
    for (int blk = 0; blk < 32; ++blk) {
      const float* gp = gpart + (size_t)(b*32 + blk)*32;
      s += gp[t]; m = fmaxf(m, gp[16 + t]);
    }
    float c1 = s * (1.0f/32768.0f) * ca_w1[t];
    float c2 = m * ca_w1[t];
    c1 += __shfl_xor(c1, 1); c1 += __shfl_xor(c1, 2); c1 += __shfl_xor(c1, 4); c1 += __shfl_xor(c1, 8);
    c2 += __shfl_xor(c2, 1); c2 += __shfl_xor(c2, 2); c2 += __shfl_xor(c2, 4); c2 += __shfl_xor(c2, 8);
    float g1 = fmaxf(c1, 0.f) + fmaxf(c2, 0.f);
    gsh[t] = 1.f / (1.f + __expf(-g1 * ca_w2[t]));
  }
  __syncthreads();                        // gsh visible

  // stage WvpTr cb-tile: pure linear 32 KB copy (zero conflicts)
  {
    const short8* gs = (const short8*)WvpTr + cb*2048 + t;
    short8* ld = (short8*)Bs + t;
    #pragma unroll
    for (int i = 0; i < 8; ++i) ld[i*256] = gs[i*256];
  }

  // gate folded into P-fragments: k&15 = (rg&1)*8 + e
  float ge[8];
  #pragma unroll
  for (int e = 0; e < 8; ++e) ge[e] = gsh[(rg & 1)*8 + e];
  #pragma unroll
  for (int kt = 0; kt < 4; ++kt) {
    short8 v0 = bf0[kt], v1 = bf1[kt];
    #pragma unroll
    for (int e = 0; e < 8; ++e) {
      v0[e] = (short)f2b(b2f((u16)v0[e]) * ge[e]);
      v1[e] = (short)f2b(b2f((u16)v1[e]) * ge[e]);
    }
    bf0[kt] = v0; bf1[kt] = v1;
  }
  __syncthreads();                        // Bs staged

  f32x4 acc[2][8];
  #pragma unroll
  for (int i = 0; i < 2; ++i)
    #pragma unroll
    for (int j = 0; j < 8; ++j) acc[i][j] = (f32x4){0.f,0.f,0.f,0.f};

  #pragma unroll
  for (int kt = 0; kt < 4; ++kt) {
    const u16* fb = Bs + (size_t)kt*4096 + lane*8;
    #pragma unroll
    for (int ct = 0; ct < 8; ++ct) {
      short8 af = *(const short8*)(fb + ct*512);
      acc[0][ct] = __builtin_amdgcn_mfma_f32_16x16x32_bf16(af, bf0[kt], acc[0][ct], 0, 0, 0);
      acc[1][ct] = __builtin_amdgcn_mfma_f32_16x16x32_bf16(af, bf1[kt], acc[1][ct], 0, 0, 0);
    }
  }

  // C[co = cb*128 + ct*16 + rg*4 + j][m = mb*128 + w*32 + nt*16 + la] -> float4 stores
  #pragma unroll
  for (int nt = 0; nt < 2; ++nt) {
    const size_t row = (size_t)(mb*128 + w*32 + nt*16 + la);
    #pragma unroll
    for (int ct = 0; ct < 8; ++ct) {
      const int col = cb*128 + ct*16 + rg*4;
      float4 bb = *(const float4*)(bp + col);
      float4 o;
      o.x = acc[nt][ct][0] + bb.x;
      o.y = acc[nt][ct][1] + bb.y;
      o.z = acc[nt][ct][2] + bb.z;
      o.w = acc[nt][ct][3] + bb.w;
      *(float4*)(out + row*C_ + col) = o;
    }
  }
}

// ---------------- launch ----------------
extern "C" void kernel_launch(void* const* d_in, const int* in_sizes, int n_in,
                              void* d_out, int out_size, void* d_ws, size_t ws_size,
                              hipStream_t stream)
{
  const float* x       = (const float*)d_in[0];
  const float* Wq      = (const float*)d_in[1];
  const float* bq      = (const float*)d_in[2];
  const float* Wk      = (const float*)d_in[3];
  const float* bk      = (const float*)d_in[4];
  const float* Wv      = (const float*)d_in[5];
  const float* bv      = (const float*)d_in[6];
  const float* Wp      = (const float*)d_in[7];
  const float* bp      = (const float*)d_in[8];
  const float* agent_k = (const float*)d_in[9];
  const float* agent_v = (const float*)d_in[10];
  const float* ca_w1   = (const float*)d_in[11];
  const float* ca_w2   = (const float*)d_in[12];
  float* out = (float*)d_out;

  char* ws = (char*)d_ws;
  u16*   attn  = (u16*)(ws);                          // 33,554,432 B
  float* k2    = (float*)(ws + 33554432);             // 32768
  float* v2    = (float*)(ws + 33587200);             // 32768
  u16*   WqkTr = (u16*)(ws + 33619968);               // 131072
  float* bqk   = (float*)(ws + 33751040);             // 2048
  u16*   WvpTr = (u16*)(ws + 33753088);               // 131072
  float* gpart = (float*)(ws + 33884160);             // 131072

  prep_kv<<<32, 256, 0, stream>>>(agent_k, Wk, bk, agent_v, Wv, bv, k2, v2);
  prep_wqk<<<512, 128, 0, stream>>>(Wq, bq, k2, WqkTr, bqk);
  prep_wvp<<<128, 256, 0, stream>>>(Wp, v2, WvpTr);
  pass_a<<<1024, 256, 0, stream>>>(x, WqkTr, bqk, attn, gpart);
  pass_b<<<4096, 256, 0, stream>>>(attn, WvpTr, gpart, ca_w1, ca_w2, bp, out);
}